// Round 9
// baseline (2250.291 us; speedup 1.0000x reference)
//
#include <hip/hip_runtime.h>
#include <math.h>

// Problem constants (fixed by setup_inputs)
constexpr int B  = 8;
constexpr int D  = 512;
constexpr int T  = 4096;
constexpr int N  = 9;
constexpr int CS = 1024;
constexpr int CD = 8;

constexpr int TT  = 8;    // columns per block
constexpr int CPW = 2;    // columns per wave (4 waves/block)
constexpr int NBLK = 4096;

#define WN_EPS 1e-12

// ---------------- workspace layout (doubles) ----------------
// w_in_n  [N][CD][D]   : 36864
// w_out_n [N][D][CD]   : 36864
// cb_n    [N][CS][CD]  : 73728
// cb_sq   [N][CS]      : 9216
// loss partials at ws+160000 : NBLK doubles

__global__ void rvq_prep(const float* __restrict__ in_v,
                         const float* __restrict__ in_g,
                         const float* __restrict__ out_v,
                         const float* __restrict__ out_g,
                         const float* __restrict__ cb,
                         double* __restrict__ ws) {
    double* w_in_n  = ws;
    double* w_out_n = ws + N * CD * D;
    double* cb_n    = ws + 2 * N * CD * D;
    double* cb_sq   = cb_n + N * CS * CD;

    int blk = blockIdx.x;
    int tid = threadIdx.x;

    if (blk == 0) {
        int row = tid;                       // 72 rows of length 512
        if (row < N * CD) {
            const float* v = in_v + (size_t)row * D;
            double s = 0.0;
            for (int j = 0; j < D; ++j) { double x = (double)v[j]; s += x * x; }
            double denom = fmax(sqrt(s), WN_EPS);
            double g = (double)in_g[row];
            for (int j = 0; j < D; ++j)
                w_in_n[(size_t)row * D + j] = (g * (double)v[j]) / denom;
        }
    } else if (blk <= 18) {
        int row = (blk - 1) * 256 + tid;     // 4608 rows of length 8
        if (row < N * D) {
            const float* v = out_v + (size_t)row * CD;
            double s = 0.0;
            #pragma unroll
            for (int k = 0; k < CD; ++k) { double x = (double)v[k]; s += x * x; }
            double denom = fmax(sqrt(s), WN_EPS);
            double g = (double)out_g[row];
            #pragma unroll
            for (int k = 0; k < CD; ++k)
                w_out_n[(size_t)row * CD + k] = (g * (double)v[k]) / denom;
        }
    } else {
        int row = (blk - 19) * 256 + tid;    // 9216 rows of length 8
        if (row < N * CS) {
            const float* v = cb + (size_t)row * CD;
            double s = 0.0;
            #pragma unroll
            for (int k = 0; k < CD; ++k) { double x = (double)v[k]; s += x * x; }
            double denom = fmax(sqrt(s), WN_EPS);
            double sq = 0.0;
            #pragma unroll
            for (int k = 0; k < CD; ++k) {
                double e = (double)v[k] / denom;
                cb_n[(size_t)row * CD + k] = e;
                sq += e * e;
            }
            cb_sq[row] = sq;
        }
    }
}

// ---- cross-lane helpers (wave64); CTRL must be a literal ----
template<int CTRL>
__device__ inline double dpp_mov_f64(double x) {
    union { double d; int i[2]; } u, v;
    u.d = x;
    v.i[0] = __builtin_amdgcn_update_dpp(0, u.i[0], CTRL, 0xF, 0xF, false);
    v.i[1] = __builtin_amdgcn_update_dpp(0, u.i[1], CTRL, 0xF, 0xF, false);
    return v.d;
}
template<int CTRL>
__device__ inline int dpp_mov_i32(int x) {
    return __builtin_amdgcn_update_dpp(0, x, CTRL, 0xF, 0xF, false);
}
// full-wave sum, result in all lanes.
__device__ inline double wave_allsum_f64(double x) {
    x += dpp_mov_f64<0xB1>(x);   // quad_perm(1,0,3,2)
    x += dpp_mov_f64<0x4E>(x);   // quad_perm(2,3,0,1)
    x += dpp_mov_f64<0x141>(x);  // row_half_mirror
    x += dpp_mov_f64<0x140>(x);  // row_mirror
    x += __shfl_xor(x, 16, 64);
    x += __shfl_xor(x, 32, 64);
    return x;
}

template<int CTRL>
__device__ inline void argmin_round_dpp(double& bd, int& bi) {
    double od = dpp_mov_f64<CTRL>(bd);
    int    oi = dpp_mov_i32<CTRL>(bi);
    bool t = (od < bd) || (od == bd && oi < bi);
    bd = t ? od : bd;
    bi = t ? oi : bi;
}
__device__ inline void argmin_round_shfl(double& bd, int& bi, int off) {
    double od = __shfl_xor(bd, off, 64);
    int    oi = __shfl_xor(bi, off, 64);
    bool t = (od < bd) || (od == bd && oi < bi);
    bd = t ? od : bd;
    bi = t ? oi : bi;
}

// LDS codebook HALF addressing: 512 codes; plane k at byte k*4096; element
// (c,k) at k*4096 + ((c*8) ^ ((k&3)<<5)). Bijective; staging writes and scan
// reads both land at the b64 2-lanes/bank floor.
__device__ inline int cbl_off(int c, int k) {
    return k * 4096 + ((c * 8) ^ ((k & 3) << 5));
}

__global__ __launch_bounds__(256)
void rvq_main(const float* __restrict__ z,
              const float* __restrict__ in_b,
              const float* __restrict__ out_b,
              const float* __restrict__ cb,
              const double* __restrict__ ws,
              double* __restrict__ wsl,
              float* __restrict__ out) {
    const double* w_in_n  = ws;
    const double* w_out_n = ws + N * CD * D;
    const double* cb_n    = ws + 2 * N * CD * D;
    const double* cb_sq   = cb_n + N * CS * CD;

    extern __shared__ char lds[];            // 32768 B dynamic
    float* zt = (float*)lds;                 // [512][9] f32 transpose scratch (18 KB)

    const int tid = threadIdx.x;             // 256 threads = 4 waves
    const int l   = tid & 63;
    const int w   = tid >> 6;
    const int blk = blockIdx.x;              // 4096
    const int b   = blk >> 9;                // 512 blocks per batch
    const int t0  = (blk & 511) * TT;
    const int tw  = t0 + w * CPW;            // this wave's first column

    // ---- transpose z into zt (coalesced global reads) ----
    {
        const float* zb = z + (size_t)b * D * T + t0;
        #pragma unroll 4
        for (int rr = 0; rr < 16; ++rr) {
            int e = rr * 256 + tid;
            int d = e >> 3, c = e & 7;
            zt[d * 9 + c] = zb[(size_t)d * T + c];
        }
    }
    __syncthreads();

    // ---- residual in registers: r[cc][j] holds d = l + 64*j of column tw+cc ----
    double r[CPW][8];
    #pragma unroll
    for (int cc = 0; cc < CPW; ++cc)
        #pragma unroll
        for (int j = 0; j < 8; ++j)
            r[cc][j] = (double)zt[(l + 64 * j) * 9 + (w * CPW + cc)];
    __syncthreads();   // zt dead; lds becomes the codebook half-buffer

    double ze[CD][CPW];
    double wloss = 0.0;

    float* codes_out = out + (size_t)B * D * T;
    float* lat_out   = codes_out + (size_t)B * N * T;

    for (int i = 0; i < N; ++i) {
        // ---- stage codebook half 0 (codes 0..511); loads overlap in-proj ----
        {
            const double* src = cb_n + (size_t)i * CS * CD;
            #pragma unroll 2
            for (int rr = 0; rr < 16; ++rr) {
                int e = rr * 256 + tid;      // e = c*8 + k, c in [0,512)
                int c = e >> 3, k = e & 7;
                *(double*)(lds + cbl_off(c, k)) = src[e];
            }
        }

        // ---- in-proj: z_e[k][col] = sum_d w_in[k][d] * r[d][col] + b ----
        const double* Wi = w_in_n + (size_t)i * CD * D;
        #pragma unroll 2
        for (int k = 0; k < CD; ++k) {
            const double* wk = Wi + (size_t)k * D + l;
            double p0 = 0.0, p1 = 0.0;
            #pragma unroll
            for (int j = 0; j < 8; ++j) {
                double wv = wk[64 * j];
                p0 = fma(wv, r[0][j], p0);
                p1 = fma(wv, r[1][j], p1);
            }
            double bias = (double)in_b[i * CD + k];
            ze[k][0] = wave_allsum_f64(p0) + bias;
            ze[k][1] = wave_allsum_f64(p1) + bias;
        }

        // ---- latents (lane 0 of each wave writes 8 float2) ----
        if (l == 0) {
            #pragma unroll
            for (int k = 0; k < CD; ++k) {
                float2 v = make_float2((float)ze[k][0], (float)ze[k][1]);
                *(float2*)&lat_out[((size_t)b * N * CD + (size_t)i * CD + k) * T + tw] = v;
            }
        }

        // ---- per-column normalize constants ----
        double es[CPW], m2i[CPW];
        #pragma unroll
        for (int cc = 0; cc < CPW; ++cc) {
            double s = 0.0;
            #pragma unroll
            for (int k = 0; k < CD; ++k) s = fma(ze[k][cc], ze[k][cc], s);
            double denom = fmax(sqrt(s), WN_EPS);
            double inv = 1.0 / denom;
            es[cc]  = s * inv * inv;
            m2i[cc] = -2.0 * inv;
        }

        // ---- two-pass distance scan over codebook halves ----
        const double* Cq = cb_sq + (size_t)i * CS;
        double best[CPW];
        int    bcode[CPW];
        #pragma unroll
        for (int cc = 0; cc < CPW; ++cc) { best[cc] = __builtin_inf(); bcode[cc] = 0; }

        #pragma unroll 1
        for (int h = 0; h < 2; ++h) {
            __syncthreads();   // half h staged (h=0: overlapped with in-proj)

            #pragma unroll 1
            for (int g = 0; g < 8; ++g) {
                int cl = l + 64 * g;          // local code in [0,512)
                int c  = h * 512 + cl;        // global code index
                double row[CD];
                #pragma unroll
                for (int k = 0; k < CD; ++k)
                    row[k] = *(const double*)(lds + cbl_off(cl, k));
                double cq = Cq[c];
                #pragma unroll
                for (int cc = 0; cc < CPW; ++cc) {
                    double dot = 0.0;
                    #pragma unroll
                    for (int k = 0; k < CD; ++k) dot = fma(ze[k][cc], row[k], dot);
                    double dist = fma(m2i[cc], dot, es[cc]) + cq;
                    bool take = (dist < best[cc]);   // ascending c: first-min
                    best[cc]  = take ? dist : best[cc];
                    bcode[cc] = take ? c : bcode[cc];
                }
            }
            __syncthreads();   // scan of half h done

            // stage half 1 while results of half 0 are merged next iteration
            if (h == 0) {
                const double* src = cb_n + (size_t)i * CS * CD + 512 * CD;
                #pragma unroll 2
                for (int rr = 0; rr < 16; ++rr) {
                    int e = rr * 256 + tid;
                    int c = e >> 3, k = e & 7;
                    *(double*)(lds + cbl_off(c, k)) = src[e];
                }
            }
        }

        // ---- argmin butterfly across 64 lanes (first-min tie-break) ----
        #pragma unroll
        for (int cc = 0; cc < CPW; ++cc) {
            double bd = best[cc]; int bi = bcode[cc];
            argmin_round_dpp<0xB1>(bd, bi);
            argmin_round_dpp<0x4E>(bd, bi);
            argmin_round_dpp<0x141>(bd, bi);
            argmin_round_dpp<0x140>(bd, bi);
            argmin_round_shfl(bd, bi, 16);
            argmin_round_shfl(bd, bi, 32);
            best[cc] = bd; bcode[cc] = bi;
        }

        // ---- codes (lane 0, one float2 per wave) ----
        if (l == 0) {
            float2 v = make_float2((float)bcode[0], (float)bcode[1]);
            *(float2*)&codes_out[((size_t)b * N + i) * T + tw] = v;
        }

        // ---- gather raw code + loss + straight-through (q overwrites ze) ----
        const float* Cb = cb + (size_t)i * CS * CD;
        #pragma unroll
        for (int cc = 0; cc < CPW; ++cc) {
            int ui = __builtin_amdgcn_readfirstlane(bcode[cc]);
            const float* crow = Cb + (size_t)ui * CD;
            #pragma unroll
            for (int k = 0; k < CD; ++k) {
                double cv = (double)crow[k];
                double zv = ze[k][cc];
                double df = zv - cv;
                wloss = fma(df, df, wloss);
                ze[k][cc] = zv + (cv - zv);    // z_e + (z_q_i - z_e)
            }
        }

        // ---- out-proj + residual update ----
        const double* Wo = w_out_n + (size_t)i * D * CD;
        #pragma unroll 2
        for (int j = 0; j < 8; ++j) {
            int d = l + 64 * j;
            const double* wr = Wo + (size_t)d * CD;
            double w0 = wr[0], w1 = wr[1], w2 = wr[2], w3 = wr[3];
            double w4 = wr[4], w5 = wr[5], w6 = wr[6], w7 = wr[7];
            double bias = (double)out_b[i * D + d];
            #pragma unroll
            for (int cc = 0; cc < CPW; ++cc) {
                double o = 0.0;
                o = fma(w0, ze[0][cc], o);
                o = fma(w1, ze[1][cc], o);
                o = fma(w2, ze[2][cc], o);
                o = fma(w3, ze[3][cc], o);
                o = fma(w4, ze[4][cc], o);
                o = fma(w5, ze[5][cc], o);
                o = fma(w6, ze[6][cc], o);
                o = fma(w7, ze[7][cc], o);
                o += bias;
                r[cc][j] -= o;
            }
        }
        __syncthreads();   // everyone done with this stage's LDS before restage
    }

    // ---- final: r -> zt (f32), then coalesced z_q = z - r ----
    #pragma unroll
    for (int cc = 0; cc < CPW; ++cc)
        #pragma unroll
        for (int j = 0; j < 8; ++j)
            zt[(l + 64 * j) * 9 + (w * CPW + cc)] = (float)r[cc][j];
    __syncthreads();
    {
        const float* zb = z + (size_t)b * D * T + t0;
        float* ob = out + (size_t)b * D * T + t0;
        #pragma unroll 4
        for (int rr = 0; rr < 16; ++rr) {
            int e = rr * 256 + tid;
            int d = e >> 3, c = e & 7;
            ob[(size_t)d * T + c] = zb[(size_t)d * T + c] - zt[d * 9 + c];
        }
    }

    // ---- per-block loss partial (wloss is wave-uniform) ----
    __syncthreads();
    double* wl = (double*)lds;
    if (l == 0) wl[w] = wloss;
    __syncthreads();
    if (tid == 0) wsl[blk] = (wl[0] + wl[1]) + (wl[2] + wl[3]);
}

__global__ void rvq_loss_reduce(const double* __restrict__ wsl,
                                float* __restrict__ out) {
    __shared__ double sm[4];
    int tid = threadIdx.x;
    double s = 0.0;
    for (int e = tid; e < NBLK; e += 256) s += wsl[e];
    for (int off = 32; off; off >>= 1) s += __shfl_xor(s, off, 64);
    if ((tid & 63) == 0) sm[tid >> 6] = s;
    __syncthreads();
    if (tid == 0) {
        double tot = ((sm[0] + sm[1]) + (sm[2] + sm[3])) * (1.0 / 262144.0);
        float* lossp = out + (size_t)B * D * T + (size_t)B * N * T + (size_t)B * N * CD * T;
        lossp[0] = (float)tot;   // commitment
        lossp[1] = (float)tot;   // codebook (identical in eval forward)
    }
}

extern "C" void kernel_launch(void* const* d_in, const int* in_sizes, int n_in,
                              void* d_out, int out_size, void* d_ws, size_t ws_size,
                              hipStream_t stream) {
    const float* z     = (const float*)d_in[0];
    const float* in_v  = (const float*)d_in[1];
    const float* in_g  = (const float*)d_in[2];
    const float* in_b  = (const float*)d_in[3];
    const float* out_v = (const float*)d_in[4];
    const float* out_g = (const float*)d_in[5];
    const float* out_b = (const float*)d_in[6];
    const float* cb    = (const float*)d_in[7];
    float* out  = (float*)d_out;
    double* ws  = (double*)d_ws;
    double* wsl = ws + 160000;   // loss partials

    rvq_prep<<<55, 256, 0, stream>>>(in_v, in_g, out_v, out_g, cb, ws);
    rvq_main<<<NBLK, 256, 32768, stream>>>(z, in_b, out_b, cb, ws, wsl, out);
    rvq_loss_reduce<<<1, 256, 0, stream>>>(wsl, out);
}

// Round 10
// 1192.000 us; speedup vs baseline: 1.8878x; 1.8878x over previous
//
#include <hip/hip_runtime.h>
#include <math.h>

// Problem constants (fixed by setup_inputs)
constexpr int B  = 8;
constexpr int D  = 512;
constexpr int T  = 4096;
constexpr int N  = 9;
constexpr int CS = 1024;
constexpr int CD = 8;

constexpr int TT  = 16;   // columns per block
constexpr int CPW = 2;    // columns per wave (8 waves/block)
constexpr int NBLK = 2048;

#define WN_EPS 1e-12

// ---------------- workspace layout (doubles) ----------------
// w_in_n  [N][CD][D]   : 36864
// w_out_t [N][CD][D]   : 36864   (TRANSPOSED: [k][d] for coalesced out-proj)
// cb_n    [N][CS][CD]  : 73728
// cb_sq   [N][CS]      : 9216
// loss partials at ws+160000 : NBLK doubles

__global__ void rvq_prep(const float* __restrict__ in_v,
                         const float* __restrict__ in_g,
                         const float* __restrict__ out_v,
                         const float* __restrict__ out_g,
                         const float* __restrict__ cb,
                         double* __restrict__ ws) {
    double* w_in_n  = ws;
    double* w_out_t = ws + N * CD * D;
    double* cb_n    = ws + 2 * N * CD * D;
    double* cb_sq   = cb_n + N * CS * CD;

    int blk = blockIdx.x;
    int tid = threadIdx.x;

    if (blk == 0) {
        int row = tid;                       // 72 rows of length 512
        if (row < N * CD) {
            const float* v = in_v + (size_t)row * D;
            double s = 0.0;
            for (int j = 0; j < D; ++j) { double x = (double)v[j]; s += x * x; }
            double denom = fmax(sqrt(s), WN_EPS);
            double g = (double)in_g[row];
            for (int j = 0; j < D; ++j)
                w_in_n[(size_t)row * D + j] = (g * (double)v[j]) / denom;
        }
    } else if (blk <= 18) {
        int row = (blk - 1) * 256 + tid;     // 4608 rows (i,d) of length 8
        if (row < N * D) {
            const float* v = out_v + (size_t)row * CD;
            int i = row / D, d = row % D;
            double s = 0.0;
            #pragma unroll
            for (int k = 0; k < CD; ++k) { double x = (double)v[k]; s += x * x; }
            double denom = fmax(sqrt(s), WN_EPS);
            double g = (double)out_g[row];
            #pragma unroll
            for (int k = 0; k < CD; ++k)
                w_out_t[((size_t)i * CD + k) * D + d] = (g * (double)v[k]) / denom;
        }
    } else {
        int row = (blk - 19) * 256 + tid;    // 9216 rows of length 8
        if (row < N * CS) {
            const float* v = cb + (size_t)row * CD;
            double s = 0.0;
            #pragma unroll
            for (int k = 0; k < CD; ++k) { double x = (double)v[k]; s += x * x; }
            double denom = fmax(sqrt(s), WN_EPS);
            double sq = 0.0;
            #pragma unroll
            for (int k = 0; k < CD; ++k) {
                double e = (double)v[k] / denom;
                cb_n[(size_t)row * CD + k] = e;
                sq += e * e;
            }
            cb_sq[row] = sq;
        }
    }
}

// ---- cross-lane helpers (wave64); CTRL must be a literal ----
template<int CTRL>
__device__ inline double dpp_mov_f64(double x) {
    union { double d; int i[2]; } u, v;
    u.d = x;
    v.i[0] = __builtin_amdgcn_update_dpp(0, u.i[0], CTRL, 0xF, 0xF, false);
    v.i[1] = __builtin_amdgcn_update_dpp(0, u.i[1], CTRL, 0xF, 0xF, false);
    return v.d;
}
template<int CTRL>
__device__ inline int dpp_mov_i32(int x) {
    return __builtin_amdgcn_update_dpp(0, x, CTRL, 0xF, 0xF, false);
}
// full-wave sum, result in all lanes.
__device__ inline double wave_allsum_f64(double x) {
    x += dpp_mov_f64<0xB1>(x);   // quad_perm(1,0,3,2)
    x += dpp_mov_f64<0x4E>(x);   // quad_perm(2,3,0,1)
    x += dpp_mov_f64<0x141>(x);  // row_half_mirror
    x += dpp_mov_f64<0x140>(x);  // row_mirror
    x += __shfl_xor(x, 16, 64);
    x += __shfl_xor(x, 32, 64);
    return x;
}

template<int CTRL>
__device__ inline void argmin_round_dpp(double& bd, int& bi) {
    double od = dpp_mov_f64<CTRL>(bd);
    int    oi = dpp_mov_i32<CTRL>(bi);
    bool t = (od < bd) || (od == bd && oi < bi);
    bd = t ? od : bd;
    bi = t ? oi : bi;
}
__device__ inline void argmin_round_shfl(double& bd, int& bi, int off) {
    double od = __shfl_xor(bd, off, 64);
    int    oi = __shfl_xor(bi, off, 64);
    bool t = (od < bd) || (od == bd && oi < bi);
    bd = t ? od : bd;
    bi = t ? oi : bi;
}

// LDS codebook HALF addressing: 512 codes; plane k at byte k*4096.
// XOR terms make BOTH the staged write pattern and the scan read pattern
// conflict-free (b64 floor).
__device__ inline int cbl_off(int c, int k) {
    return k * 4096 + ((c * 8) ^ ((k & 3) << 5) ^ ((k >> 2) << 4));
}

__global__ __launch_bounds__(512)
void rvq_main(const float* __restrict__ z,
              const float* __restrict__ in_b,
              const float* __restrict__ out_b,
              const float* __restrict__ cb,
              const double* __restrict__ ws,
              double* __restrict__ wsl,
              float* __restrict__ out) {
    const double* w_in_n  = ws;
    const double* w_out_t = ws + N * CD * D;
    const double* cb_n    = ws + 2 * N * CD * D;
    const double* cb_sq   = cb_n + N * CS * CD;

    extern __shared__ char lds[];            // 32768 B dynamic
    float* zt = (float*)lds;                 // [256][17] f32 transpose scratch (17.4 KB)

    const int tid = threadIdx.x;             // 512 threads = 8 waves
    const int l   = tid & 63;
    const int w   = tid >> 6;
    const int blk = blockIdx.x;              // 2048
    const int b   = blk >> 8;                // 256 blocks per batch
    const int t0  = (blk & 255) * TT;
    const int tw  = t0 + w * CPW;            // this wave's first column

    double r[CPW][8];

    // ---- transpose z in two d-halves (coalesced global reads) ----
    {
        const float* zb = z + (size_t)b * D * T + t0;
        #pragma unroll 2
        for (int rr = 0; rr < 8; ++rr) {      // d in [0,256)
            int e = rr * 512 + tid;
            int d = e >> 4, c = e & 15;
            zt[d * 17 + c] = zb[(size_t)d * T + c];
        }
        __syncthreads();
        #pragma unroll
        for (int cc = 0; cc < CPW; ++cc)
            #pragma unroll
            for (int j = 0; j < 4; ++j)
                r[cc][j] = (double)zt[(l + 64 * j) * 17 + (w * CPW + cc)];
        __syncthreads();
        #pragma unroll 2
        for (int rr = 0; rr < 8; ++rr) {      // d in [256,512)
            int e = rr * 512 + tid;
            int d = e >> 4, c = e & 15;
            zt[d * 17 + c] = zb[(size_t)(d + 256) * T + c];
        }
        __syncthreads();
        #pragma unroll
        for (int cc = 0; cc < CPW; ++cc)
            #pragma unroll
            for (int j = 4; j < 8; ++j)
                r[cc][j] = (double)zt[(l + 64 * (j - 4)) * 17 + (w * CPW + cc)];
        __syncthreads();   // zt dead; lds becomes the codebook half-buffer
    }

    double ze[CD][CPW];
    double wloss = 0.0;

    float* codes_out = out + (size_t)B * D * T;
    float* lat_out   = codes_out + (size_t)B * N * T;

    for (int i = 0; i < N; ++i) {
        const double* srcCB = cb_n + (size_t)i * CS * CD;

        // ---- prefetch codebook half 0 into regs (latency hides under in-proj) ----
        double ph[8];
        #pragma unroll
        for (int q = 0; q < 8; ++q) ph[q] = srcCB[q * 512 + tid];

        // ---- in-proj: z_e[k][col] = sum_d w_in[k][d] * r[d][col] + b ----
        const double* Wi = w_in_n + (size_t)i * CD * D;
        #pragma unroll 2
        for (int k = 0; k < CD; ++k) {
            const double* wk = Wi + (size_t)k * D + l;
            double p0 = 0.0, p1 = 0.0;
            #pragma unroll
            for (int j = 0; j < 8; ++j) {
                double wv = wk[64 * j];
                p0 = fma(wv, r[0][j], p0);
                p1 = fma(wv, r[1][j], p1);
            }
            double bias = (double)in_b[i * CD + k];
            ze[k][0] = wave_allsum_f64(p0) + bias;
            ze[k][1] = wave_allsum_f64(p1) + bias;
        }

        // ---- ds_write half 0; prefetch half 1 into regs ----
        #pragma unroll
        for (int q = 0; q < 8; ++q) {
            int e = q * 512 + tid;
            int c = e >> 3, k = e & 7;
            *(double*)(lds + cbl_off(c, k)) = ph[q];
        }
        #pragma unroll
        for (int q = 0; q < 8; ++q) ph[q] = srcCB[4096 + q * 512 + tid];

        // ---- latents (lane 0 of each wave writes 8 float2) ----
        if (l == 0) {
            #pragma unroll
            for (int k = 0; k < CD; ++k) {
                float2 v = make_float2((float)ze[k][0], (float)ze[k][1]);
                *(float2*)&lat_out[((size_t)b * N * CD + (size_t)i * CD + k) * T + tw] = v;
            }
        }

        // ---- per-column normalize constants ----
        double es[CPW], m2i[CPW];
        #pragma unroll
        for (int cc = 0; cc < CPW; ++cc) {
            double s = 0.0;
            #pragma unroll
            for (int k = 0; k < CD; ++k) s = fma(ze[k][cc], ze[k][cc], s);
            double denom = fmax(sqrt(s), WN_EPS);
            double inv = 1.0 / denom;
            es[cc]  = s * inv * inv;
            m2i[cc] = -2.0 * inv;
        }

        const double* Cq = cb_sq + (size_t)i * CS;
        double best[CPW];
        int    bcode[CPW];
        #pragma unroll
        for (int cc = 0; cc < CPW; ++cc) { best[cc] = __builtin_inf(); bcode[cc] = 0; }

        __syncthreads();   // half 0 staged

        // ---- scan half 0 ----
        #pragma unroll 1
        for (int g = 0; g < 8; ++g) {
            int cl = l + 64 * g;
            double row[CD];
            #pragma unroll
            for (int k = 0; k < CD; ++k)
                row[k] = *(const double*)(lds + cbl_off(cl, k));
            double cq = Cq[cl];
            #pragma unroll
            for (int cc = 0; cc < CPW; ++cc) {
                double dot = 0.0;
                #pragma unroll
                for (int k = 0; k < CD; ++k) dot = fma(ze[k][cc], row[k], dot);
                double dist = fma(m2i[cc], dot, es[cc]) + cq;
                bool take = (dist < best[cc]);
                best[cc]  = take ? dist : best[cc];
                bcode[cc] = take ? cl : bcode[cc];
            }
        }
        __syncthreads();   // scan h0 done

        // ---- ds_write half 1 (loads already in flight since before scan h0) ----
        #pragma unroll
        for (int q = 0; q < 8; ++q) {
            int e = q * 512 + tid;
            int c = e >> 3, k = e & 7;
            *(double*)(lds + cbl_off(c, k)) = ph[q];
        }
        __syncthreads();   // half 1 staged

        // ---- scan half 1 ----
        #pragma unroll 1
        for (int g = 0; g < 8; ++g) {
            int cl = l + 64 * g;
            int c  = 512 + cl;
            double row[CD];
            #pragma unroll
            for (int k = 0; k < CD; ++k)
                row[k] = *(const double*)(lds + cbl_off(cl, k));
            double cq = Cq[c];
            #pragma unroll
            for (int cc = 0; cc < CPW; ++cc) {
                double dot = 0.0;
                #pragma unroll
                for (int k = 0; k < CD; ++k) dot = fma(ze[k][cc], row[k], dot);
                double dist = fma(m2i[cc], dot, es[cc]) + cq;
                bool take = (dist < best[cc]);   // strict <: h0/lower idx wins ties
                best[cc]  = take ? dist : best[cc];
                bcode[cc] = take ? c : bcode[cc];
            }
        }

        // ---- argmin butterfly across 64 lanes (first-min tie-break) ----
        #pragma unroll
        for (int cc = 0; cc < CPW; ++cc) {
            double bd = best[cc]; int bi = bcode[cc];
            argmin_round_dpp<0xB1>(bd, bi);
            argmin_round_dpp<0x4E>(bd, bi);
            argmin_round_dpp<0x141>(bd, bi);
            argmin_round_dpp<0x140>(bd, bi);
            argmin_round_shfl(bd, bi, 16);
            argmin_round_shfl(bd, bi, 32);
            best[cc] = bd; bcode[cc] = bi;
        }

        // ---- codes (lane 0, one float2 per wave) ----
        if (l == 0) {
            float2 v = make_float2((float)bcode[0], (float)bcode[1]);
            *(float2*)&codes_out[((size_t)b * N + i) * T + tw] = v;
        }

        // ---- gather raw code + loss + straight-through (q overwrites ze) ----
        const float* Cb = cb + (size_t)i * CS * CD;
        #pragma unroll
        for (int cc = 0; cc < CPW; ++cc) {
            int ui = __builtin_amdgcn_readfirstlane(bcode[cc]);
            const float* crow = Cb + (size_t)ui * CD;
            #pragma unroll
            for (int k = 0; k < CD; ++k) {
                double cv = (double)crow[k];
                double zv = ze[k][cc];
                double df = zv - cv;
                wloss = fma(df, df, wloss);
                ze[k][cc] = zv + (cv - zv);    // z_e + (z_q_i - z_e)
            }
        }

        // ---- out-proj (w_out transposed: coalesced loads) + residual update ----
        const double* Wo = w_out_t + (size_t)i * CD * D;
        #pragma unroll 2
        for (int j = 0; j < 8; ++j) {
            int d = l + 64 * j;
            double wv[CD];
            #pragma unroll
            for (int k = 0; k < CD; ++k) wv[k] = Wo[(size_t)k * D + d];
            double bias = (double)out_b[i * D + d];
            #pragma unroll
            for (int cc = 0; cc < CPW; ++cc) {
                double o = 0.0;
                #pragma unroll
                for (int k = 0; k < CD; ++k) o = fma(wv[k], ze[k][cc], o);
                o += bias;
                r[cc][j] -= o;
            }
        }
        __syncthreads();   // everyone done with LDS before next stage restages
    }

    // ---- final: z_q = z - r, via two-half transpose (coalesced writes) ----
    {
        const float* zb = z + (size_t)b * D * T + t0;
        float* ob = out + (size_t)b * D * T + t0;
        #pragma unroll
        for (int cc = 0; cc < CPW; ++cc)
            #pragma unroll
            for (int j = 0; j < 4; ++j)
                zt[(l + 64 * j) * 17 + (w * CPW + cc)] = (float)r[cc][j];
        __syncthreads();
        #pragma unroll 2
        for (int rr = 0; rr < 8; ++rr) {
            int e = rr * 512 + tid;
            int d = e >> 4, c = e & 15;
            ob[(size_t)d * T + c] = zb[(size_t)d * T + c] - zt[d * 17 + c];
        }
        __syncthreads();
        #pragma unroll
        for (int cc = 0; cc < CPW; ++cc)
            #pragma unroll
            for (int j = 4; j < 8; ++j)
                zt[(l + 64 * (j - 4)) * 17 + (w * CPW + cc)] = (float)r[cc][j];
        __syncthreads();
        #pragma unroll 2
        for (int rr = 0; rr < 8; ++rr) {
            int e = rr * 512 + tid;
            int d = e >> 4, c = e & 15;
            ob[(size_t)(d + 256) * T + c] = zb[(size_t)(d + 256) * T + c] - zt[d * 17 + c];
        }
    }

    // ---- per-block loss partial (wloss is wave-uniform) ----
    __syncthreads();
    double* wl = (double*)lds;
    if (l == 0) wl[w] = wloss;
    __syncthreads();
    if (tid == 0) {
        double s = 0.0;
        #pragma unroll
        for (int ww = 0; ww < 8; ++ww) s += wl[ww];
        wsl[blk] = s;
    }
}

__global__ void rvq_loss_reduce(const double* __restrict__ wsl,
                                float* __restrict__ out) {
    __shared__ double sm[4];
    int tid = threadIdx.x;
    double s = 0.0;
    for (int e = tid; e < NBLK; e += 256) s += wsl[e];
    for (int off = 32; off; off >>= 1) s += __shfl_xor(s, off, 64);
    if ((tid & 63) == 0) sm[tid >> 6] = s;
    __syncthreads();
    if (tid == 0) {
        double tot = ((sm[0] + sm[1]) + (sm[2] + sm[3])) * (1.0 / 262144.0);
        float* lossp = out + (size_t)B * D * T + (size_t)B * N * T + (size_t)B * N * CD * T;
        lossp[0] = (float)tot;   // commitment
        lossp[1] = (float)tot;   // codebook (identical in eval forward)
    }
}

extern "C" void kernel_launch(void* const* d_in, const int* in_sizes, int n_in,
                              void* d_out, int out_size, void* d_ws, size_t ws_size,
                              hipStream_t stream) {
    const float* z     = (const float*)d_in[0];
    const float* in_v  = (const float*)d_in[1];
    const float* in_g  = (const float*)d_in[2];
    const float* in_b  = (const float*)d_in[3];
    const float* out_v = (const float*)d_in[4];
    const float* out_g = (const float*)d_in[5];
    const float* out_b = (const float*)d_in[6];
    const float* cb    = (const float*)d_in[7];
    float* out  = (float*)d_out;
    double* ws  = (double*)d_ws;
    double* wsl = ws + 160000;   // loss partials

    rvq_prep<<<55, 256, 0, stream>>>(in_v, in_g, out_v, out_g, cb, ws);
    rvq_main<<<NBLK, 512, 32768, stream>>>(z, in_b, out_b, cb, ws, wsl, out);
    rvq_loss_reduce<<<1, 256, 0, stream>>>(wsl, out);
}